// Round 17
// baseline (370.761 us; speedup 1.0000x reference)
//
#include <hip/hip_runtime.h>

// Problem dims
#define B_  32
#define N_  1024
#define E_  1024
#define H_  8
#define D_  128
#define MID_ 64
#define NT_  32        // n-tiles for score+pool (32 rows each)
#define NSP_ 32        // v2-pool split rows

// Journal (counter-backed lessons):
//  R3: never replay a stream. R4: never scale same-dest atomic writers.
//  R5/R6: VGPR=64 cap + big live-set = spill; plain launch_bounds only.
//  R7: fp32 scorepool 92us / VGPR 72 / bytes ideal.
//  R9: live-set arithmetic BEFORE benching. R10: interleave degrades both.
//  R11: weight batching moved nothing. R12: mega-kernel = spill dead end;
//      ~240us/iter is HARNESS-FIXED (512MB re-poison fills @77us + chain).
//  R13: LDS-only barriers NULL. R14: NT=64 NULL.
//  R15: MFMA dots: k_main ~75, total 353.4 (best). floor ~55-60 kernels.
//  R16: double-buffer pipeline REGRESSED (89us): LDS 56KB -> 2 blk/CU,
//      VGPR 124, outer's key re-read aged out of L2 (FETCH 124MB).
//  R17: revert dots to R15; SPLIT k_main -> k_dots (scores -> 1MB sg) +
//      k_outer (rank-8 update). key 128MB < 256MB L3: k_outer's re-read is
//      L3-resident by construction (k_dots streamed it just before).

typedef __attribute__((ext_vector_type(8))) short bf16x8;
typedef __attribute__((ext_vector_type(4))) float f32x4;

// fp32 -> 2x bf16 packed (round-to-nearest-even)
__device__ __forceinline__ unsigned bf2(float a, float b) {
    unsigned ua = __float_as_uint(a);
    ua = (ua + 0x7fffu + ((ua >> 16) & 1u)) >> 16;
    unsigned ub = __float_as_uint(b);
    ub = (ub + 0x7fffu + ((ub >> 16) & 1u)) >> 16;
    return ua | (ub << 16);
}

// ---------------------------------------------------------------------------
// k_q: blocks [0,256): Qs = query@Wq^T + bq (batched: 8 b x 16 rows/block);
//      blocks [256,1280): v2 pooling (independent stream, overlaps).
// ---------------------------------------------------------------------------
__global__ __launch_bounds__(256) void k_q(
        const float* __restrict__ query, const float* __restrict__ Wq,
        const float* __restrict__ bq, const float* __restrict__ bk,
        float* __restrict__ Qs, float* __restrict__ qb,
        const float* __restrict__ value2, const int* __restrict__ mask,
        float* __restrict__ P2p)
{
    const int t = threadIdx.x;

    __shared__ __align__(16) float qsh[8 * E_];   // 32 KB: 8 query rows
    __shared__ __align__(16) float Qrow[8][16];   // [bb][r]
    __shared__ int rows[NSP_];
    __shared__ int nrows;

    if (blockIdx.x < 256) {
        const int bg = blockIdx.x >> 6;        // 0..3 -> b0 = bg*8
        const int rs = blockIdx.x & 63;        // 0..63 -> rows rs*16
        const int b0 = bg * 8;
        const int R  = rs * 16;
        const int h  = rs >> 3;

        {
            const int bb = t >> 5, ln = t & 31;
            const float4* src = (const float4*)(query + (size_t)(b0 + bb) * E_);
            float4* dst = (float4*)(qsh + bb * E_);
            #pragma unroll
            for (int i = 0; i < 8; ++i) dst[ln + i * 32] = src[ln + i * 32];
        }
        __syncthreads();

        const int r = t >> 4, cl = t & 15;
        const int row = R + r;
        const float4* wr = (const float4*)(Wq + (size_t)row * E_);
        float4 wchunk[16];
        #pragma unroll
        for (int i = 0; i < 16; ++i) wchunk[i] = wr[cl + i * 16];

        const float bqv = bq[row];
        const float4* qsh4 = (const float4*)qsh;
        #pragma unroll
        for (int bb = 0; bb < 8; ++bb) {
            float acc = 0.f;
            #pragma unroll
            for (int i = 0; i < 16; ++i) {
                float4 q = qsh4[bb * 256 + cl + i * 16];
                acc += wchunk[i].x * q.x + wchunk[i].y * q.y
                     + wchunk[i].z * q.z + wchunk[i].w * q.w;
            }
            #pragma unroll
            for (int off = 8; off; off >>= 1) acc += __shfl_xor(acc, off);
            if (cl == 0) Qrow[bb][r] = acc + bqv;
        }
        __syncthreads();

        if (t < 8) {
            float s = 0.f;
            #pragma unroll
            for (int rr = 0; rr < 16; ++rr) s += Qrow[t][rr] * bk[R + rr];
            atomicAdd(&qb[(b0 + t) * 8 + h], s);
        }
        if (t < 32) {
            const int bb = t >> 2, j = t & 3;
            ((float4*)(Qs + (size_t)(b0 + bb) * E_))[rs * 4 + j] =
                *(const float4*)&Qrow[bb][j * 4];
        }
    } else {
        // ---- v2 pooling: 32-row split; P2p[sp&7] partials
        const int pi = blockIdx.x - 256;        // [0,1024)
        const int b = pi & 31, sp = pi >> 5;
        const int e0 = t * 4;
        const int n0 = sp * NSP_;

        if (t == 0) nrows = 0;
        __syncthreads();
        if (t < NSP_) {
            if (mask[b * N_ + n0 + t]) {
                int i2 = atomicAdd(&nrows, 1);
                rows[i2] = t;
            }
        }
        __syncthreads();
        const int nr = nrows;

        float a0 = 0.f, a1 = 0.f, a2 = 0.f, a3 = 0.f;
        const float* vb = value2 + ((size_t)(b * N_ + n0)) * E_ + e0;
        #pragma unroll 4
        for (int i = 0; i < nr; ++i) {
            float4 v = *(const float4*)(vb + (size_t)rows[i] * E_);
            a0 += v.x; a1 += v.y; a2 += v.z; a3 += v.w;
        }
        float* dst = P2p + ((size_t)(sp & 7) * B_ + b) * E_ + e0;
        atomicAdd(dst + 0, a0); atomicAdd(dst + 1, a1);
        atomicAdd(dst + 2, a2); atomicAdd(dst + 3, a3);
    }
}

// ---------------------------------------------------------------------------
// k_k: qkb[b,h,e] (bf16) = sum_d Qs[b,h*D+d] * Wk[h*D+d,e], LDS-tiled GEMM.
// ---------------------------------------------------------------------------
__global__ __launch_bounds__(256) void k_k(
        const float* __restrict__ Qs, const float* __restrict__ Wk,
        unsigned short* __restrict__ qkb)
{
    const int h = blockIdx.x >> 5, ec = blockIdx.x & 31;
    const int t = threadIdx.x;

    __shared__ __align__(16) float QsL[32 * 132];   // padded, 16.9 KB
    __shared__ __align__(16) float WkL[128 * 32];   // 16 KB

    {
        const int b = t >> 3, j = t & 7;
        const float4* src = (const float4*)(Qs + (size_t)b * E_) + h * 32;
        float4* dst = (float4*)(QsL + b * 132);
        #pragma unroll
        for (int jj = 0; jj < 4; ++jj) dst[j + jj * 8] = src[j + jj * 8];
    }
    {
        #pragma unroll
        for (int jj = 0; jj < 4; ++jj) {
            const int idx = t + jj * 256;
            const int d = idx >> 3, c = idx & 7;
            ((float4*)WkL)[idx] =
                ((const float4*)(Wk + (size_t)(h * D_ + d) * E_))[ec * 8 + c];
        }
    }
    __syncthreads();

    const int b = t >> 3, eg = t & 7;
    float4 acc = make_float4(0.f, 0.f, 0.f, 0.f);
    const float* q = QsL + b * 132;
    const float4* wk4 = (const float4*)WkL;
    #pragma unroll 8
    for (int d = 0; d < D_; ++d) {
        float qd = q[d];
        float4 w = wk4[d * 8 + eg];
        acc.x += qd * w.x; acc.y += qd * w.y;
        acc.z += qd * w.z; acc.w += qd * w.w;
    }
    uint2 pk;
    pk.x = bf2(acc.x, acc.y);
    pk.y = bf2(acc.z, acc.w);
    ((uint2*)(qkb + (size_t)(b * 8 + h) * E_))[ec * 8 + eg] = pk;
}

// ---------------------------------------------------------------------------
// k_dots (R15 dots phase verbatim): per (tile,b), 32-row tiles.
//   4 e-quarters: stage key(bf16, pad-264) + qkb slice -> 4 waves x 4 MFMA
//   (16x16x32 bf16), C in regs. Finalize s -> write sg[b,n,h] (1 MB) + ssum.
// grid (NT_, B_) = 1024 blocks, 256 thr, ~26 KB LDS (R15-proven occupancy).
// ---------------------------------------------------------------------------
__global__ __launch_bounds__(256) void k_dots(
        const float* __restrict__ key, const unsigned short* __restrict__ qkb,
        const float* __restrict__ qb, float* __restrict__ sg,
        float* __restrict__ ssum)
{
    const int tile = blockIdx.x, b = blockIdx.y;
    const int t = threadIdx.x;
    const int w = t >> 6, l = t & 63;

    __shared__ __align__(16) unsigned short KLs[32 * 264];  // 16.5 KB
    __shared__ __align__(16) unsigned short QLs[8 * 264];   // 4.1 KB
    __shared__ __align__(16) float part[2][2][16][16];      // 4 KB
    __shared__ __align__(16) float sfin[32][8];             // 1 KB

    const float scale = 0.08838834764831845f;  // 1/sqrt(128)
    const float* keyb = key + ((size_t)b * N_ + (size_t)tile * 32) * E_;
    const unsigned short* qkbb = qkb + (size_t)(b * 8) * E_;

    const int mtile = w & 1, ksub = w >> 1;
    const int arow = mtile * 16 + (l & 15);
    const int brow = l & 7;                 // cols>=8 duplicate valid data
    const int kgrp = (l >> 4) * 16;         // byte offset of lane's k-group

    f32x4 Cacc = {0.f, 0.f, 0.f, 0.f};

    for (int q = 0; q < 4; ++q) {
        // stage key quarter: 32 rows x 256 floats -> bf16 (coalesced)
        #pragma unroll
        for (int j = 0; j < 8; ++j) {
            const int idx = t + j * 256;
            const int row = idx >> 6, c4 = idx & 63;
            float4 v = ((const float4*)(keyb + (size_t)row * E_))[q * 64 + c4];
            uint2 pk;
            pk.x = bf2(v.x, v.y);
            pk.y = bf2(v.z, v.w);
            ((uint2*)(KLs + row * 264))[c4] = pk;
        }
        // stage qk quarter: 8 h x 256 bf16
        #pragma unroll
        for (int j = 0; j < 2; ++j) {
            const int idx = t + j * 256;
            const int h = idx >> 6, c4 = idx & 63;
            ((uint2*)(QLs + h * 264))[c4] =
                ((const uint2*)(qkbb + (size_t)h * E_))[q * 64 + c4];
        }
        __syncthreads();
        #pragma unroll
        for (int s = 0; s < 4; ++s) {
            const int koff = (ksub * 4 + s) * 64 + kgrp;   // bytes
            bf16x8 a = *(const bf16x8*)((const char*)(KLs + arow * 264) + koff);
            bf16x8 bb = *(const bf16x8*)((const char*)(QLs + brow * 264) + koff);
            Cacc = __builtin_amdgcn_mfma_f32_16x16x32_bf16(a, bb, Cacc, 0, 0, 0);
        }
        if (q < 3) __syncthreads();   // before restaging KLs/QLs
    }

    // write C partials: lane l holds S[(l>>4)*4+j][l&15] for its (mtile,ksub)
    #pragma unroll
    for (int j = 0; j < 4; ++j)
        part[mtile][ksub][(l >> 4) * 4 + j][l & 15] = Cacc[j];
    __syncthreads();

    // finalize s: thread (r = t>>3, h = t&7)
    {
        const int r = t >> 3, h = t & 7;
        const float s = (part[r >> 4][0][r & 15][h]
                       + part[r >> 4][1][r & 15][h]
                       + qb[b * 8 + h]) * scale;
        sfin[r][h] = s;
    }
    __syncthreads();

    if (t < 8) {
        float ts = 0.f;
        #pragma unroll
        for (int r = 0; r < 32; ++r) ts += sfin[r][t];
        atomicAdd(&ssum[b * 8 + t], ts);
    }

    // write s tile to global: sg[(b*N + tile*32 + r)*8 + h], coalesced over t
    sg[((size_t)(b * N_) + tile * 32) * 8 + t] = sfin[t >> 3][t & 7];
}

// ---------------------------------------------------------------------------
// k_outer (R7 outer pass): per (tile,b).
//   PP[h,e] += s[n,h]*K[n,e] over the tile's 32 rows. key is L3-resident
//   (k_dots streamed all 128 MB of it; L3 = 256 MB) -> ~6.9 TB/s reads.
// grid (NT_, B_) = 1024 blocks, 256 thr, 1 KB LDS, VGPR ~72 (R7-proven).
// ---------------------------------------------------------------------------
__global__ __launch_bounds__(256) void k_outer(
        const float* __restrict__ key, const float* __restrict__ sg,
        float* __restrict__ PPpart)
{
    const int tile = blockIdx.x, b = blockIdx.y;
    const int t = threadIdx.x;

    __shared__ __align__(16) float sfin[32][8];   // 1 KB

    sfin[t >> 3][t & 7] = sg[((size_t)(b * N_) + tile * 32) * 8 + t];
    __syncthreads();

    const float* keyb = key + ((size_t)b * N_ + (size_t)tile * 32) * E_;

    float4 pacc[8];
    #pragma unroll
    for (int h = 0; h < 8; ++h) pacc[h] = make_float4(0.f, 0.f, 0.f, 0.f);

    float4 kv[4];
    #pragma unroll
    for (int r = 0; r < 4; ++r)
        kv[r] = ((const float4*)(keyb + (size_t)r * E_))[t];

    for (int st = 0; st < 8; ++st) {
        float4 kn[4];
        if (st < 7) {
            #pragma unroll
            for (int r = 0; r < 4; ++r)
                kn[r] = ((const float4*)(keyb
                            + (size_t)((st + 1) * 4 + r) * E_))[t];
        }
        #pragma unroll
        for (int r = 0; r < 4; ++r) {
            const float4 k4 = kv[r];
            const float4 sA = *(const float4*)&sfin[st * 4 + r][0];
            const float4 sB = *(const float4*)&sfin[st * 4 + r][4];
            pacc[0].x += sA.x * k4.x; pacc[0].y += sA.x * k4.y;
            pacc[0].z += sA.x * k4.z; pacc[0].w += sA.x * k4.w;
            pacc[1].x += sA.y * k4.x; pacc[1].y += sA.y * k4.y;
            pacc[1].z += sA.y * k4.z; pacc[1].w += sA.y * k4.w;
            pacc[2].x += sA.z * k4.x; pacc[2].y += sA.z * k4.y;
            pacc[2].z += sA.z * k4.z; pacc[2].w += sA.z * k4.w;
            pacc[3].x += sA.w * k4.x; pacc[3].y += sA.w * k4.y;
            pacc[3].z += sA.w * k4.z; pacc[3].w += sA.w * k4.w;
            pacc[4].x += sB.x * k4.x; pacc[4].y += sB.x * k4.y;
            pacc[4].z += sB.x * k4.z; pacc[4].w += sB.x * k4.w;
            pacc[5].x += sB.y * k4.x; pacc[5].y += sB.y * k4.y;
            pacc[5].z += sB.y * k4.z; pacc[5].w += sB.y * k4.w;
            pacc[6].x += sB.z * k4.x; pacc[6].y += sB.z * k4.y;
            pacc[6].z += sB.z * k4.z; pacc[6].w += sB.z * k4.w;
            pacc[7].x += sB.w * k4.x; pacc[7].y += sB.w * k4.y;
            pacc[7].z += sB.w * k4.z; pacc[7].w += sB.w * k4.w;
        }
        #pragma unroll
        for (int r = 0; r < 4; ++r) kv[r] = kn[r];
    }

    #pragma unroll
    for (int h = 0; h < 8; ++h) {
        ((float4*)(PPpart
            + (((size_t)(b * H_ + h)) * NT_ + tile) * E_))[t] = pacc[h];
    }
}

// ---------------------------------------------------------------------------
// k_tail: per bh, 512 threads. reduce + Wv dots + epilogue (R13-proven).
// ---------------------------------------------------------------------------
__global__ __launch_bounds__(512) void k_tail(
        const float* __restrict__ PPpart, const float* __restrict__ P2p,
        const float* __restrict__ ssumg, const int* __restrict__ mask,
        const float* __restrict__ Wv, const float* __restrict__ bv,
        const float* __restrict__ Wb, const float* __restrict__ bb,
        const float* __restrict__ Wl2, const float* __restrict__ bl2,
        const float* __restrict__ value1, float* __restrict__ out)
{
    const int bh = blockIdx.x, b = bh >> 3, h = bh & 7;
    const int t = threadIdx.x;
    const int l = t & 63, w = t >> 6;       // 8 waves
    const int rg = l >> 4, cl = l & 15;     // 4 row-groups x 16 lanes

    __shared__ __align__(16) float ph[2][E_];
    __shared__ __align__(16) float pooled[E_];
    __shared__ __align__(16) float pool2[E_];
    __shared__ float attA_s[D_];
    __shared__ float attV_s[D_];
    __shared__ float att[D_];
    __shared__ float hv[MID_];
    __shared__ float red2[2];
    __shared__ float cnt_s;

    {
        const int c4 = t & 255, half = t >> 8;
        const float4* pp = (const float4*)(PPpart + (size_t)bh * NT_ * E_);
        float4 s = make_float4(0.f, 0.f, 0.f, 0.f);
        #pragma unroll 4
        for (int j = 0; j < 16; ++j) {
            float4 v = pp[(half * 16 + j) * 256 + c4];
            s.x += v.x; s.y += v.y; s.z += v.z; s.w += v.w;
        }
        ((float4*)&ph[half][0])[c4] = s;
    }
    __syncthreads();
    if (t < 256) {
        float4 p0 = ((const float4*)&ph[0][0])[t];
        float4 p1 = ((const float4*)&ph[1][0])[t];
        ((float4*)pooled)[t] = make_float4(p0.x + p1.x, p0.y + p1.y,
                                           p0.z + p1.z, p0.w + p1.w);
        float4 q = make_float4(0.f, 0.f, 0.f, 0.f);
        #pragma unroll
        for (int k2 = 0; k2 < 8; ++k2) {
            float4 v = ((const float4*)(P2p + ((size_t)k2 * B_ + b) * E_))[t];
            q.x += v.x; q.y += v.y; q.z += v.z; q.w += v.w;
        }
        ((float4*)pool2)[t] = q;
    }
    __syncthreads();

    const float4* pooled4 = (const float4*)pooled;
    const float4* pool24  = (const float4*)pool2;
    #pragma unroll
    for (int p = 0; p < 4; ++p) {
        const int d = p * 32 + w * 4 + rg;
        const float4* wvr = (const float4*)(Wv + (size_t)(h * D_ + d) * E_);
        float pA = 0.f, pV = 0.f;
        #pragma unroll 4
        for (int i = 0; i < 16; ++i) {
            float4 wv4 = wvr[cl + i * 16];
            float4 pa = pooled4[cl + i * 16];
            float4 pb = pool24[cl + i * 16];
            pA += wv4.x * pa.x + wv4.y * pa.y + wv4.z * pa.z + wv4.w * pa.w;
            pV += wv4.x * pb.x + wv4.y * pb.y + wv4.z * pb.z + wv4.w * pb.w;
        }
        #pragma unroll
        for (int off = 8; off; off >>= 1) {
            pA += __shfl_xor(pA, off);
            pV += __shfl_xor(pV, off);
        }
        if (cl == 0) { attA_s[d] = pA; attV_s[d] = pV; }
    }
    __syncthreads();

    if (t < 128) {
        int ci = 0;
        #pragma unroll
        for (int i = 0; i < 8; ++i) ci += mask[b * N_ + t + i * 128];
        float cf = (float)ci;
        #pragma unroll
        for (int off = 32; off; off >>= 1) cf += __shfl_down(cf, off);
        if ((t & 63) == 0) red2[t >> 6] = cf;
        const float ss = ssumg[bh];
        att[t] = attA_s[t] + ss * bv[h * D_ + t];
    }
    __syncthreads();
    if (t == 0) cnt_s = red2[0] + red2[1];
    if (t < MID_) {
        float a = bb[t];
        #pragma unroll 4
        for (int d2 = 0; d2 < D_; ++d2) a += att[d2] * Wb[t * D_ + d2];
        hv[t] = fmaxf(a, 0.f);
    }
    __syncthreads();
    if (t < 128) {
        float z = bl2[t];
        #pragma unroll
        for (int m = 0; m < MID_; ++m) z += hv[m] * Wl2[t * MID_ + m];
        float alphac = 1.f / (1.f + expf(-z));
        const float bvd = bv[h * D_ + t];
        float v2a = attV_s[t] / cnt_s + bvd;
        out[(size_t)b * E_ + h * D_ + t] =
            value1[(size_t)b * E_ + h * D_ + t] * v2a * alphac;
    }
}

// ---------------------------------------------------------------------------
extern "C" void kernel_launch(void* const* d_in, const int* in_sizes, int n_in,
                              void* d_out, int out_size, void* d_ws, size_t ws_size,
                              hipStream_t stream)
{
    const float* query  = (const float*)d_in[0];
    const float* key    = (const float*)d_in[1];
    const int*   mask   = (const int*)d_in[2];
    const float* value1 = (const float*)d_in[3];
    const float* value2 = (const float*)d_in[4];
    const float* Wq  = (const float*)d_in[5];
    const float* bq  = (const float*)d_in[6];
    const float* Wk  = (const float*)d_in[7];
    const float* bk  = (const float*)d_in[8];
    const float* Wv  = (const float*)d_in[9];
    const float* bv  = (const float*)d_in[10];
    const float* Wb  = (const float*)d_in[11];
    const float* bb  = (const float*)d_in[12];
    // d_in[13] = Wl, d_in[14] = bl: eliminated (softmax of uniform = mask/cnt)
    const float* Wl2 = (const float*)d_in[15];
    const float* bl2 = (const float*)d_in[16];
    float* out = (float*)d_out;

    // workspace layout (bytes), ~36 MB
    char* ws = (char*)d_ws;
    const size_t SZ_PPP = (size_t)B_ * H_ * NT_ * E_ * 4;     // PPpart: 32 MB
    const size_t SZ_P2P = (size_t)8 * B_ * E_ * 4;            // P2p: 1 MB
    const size_t OFF_P2P = SZ_PPP;
    const size_t OFF_SS  = OFF_P2P + SZ_P2P;                  // ssum: 1 KB
    const size_t OFF_QB  = OFF_SS + 1024;                     // qb: 1 KB
    const size_t OFF_QS  = OFF_QB + 1024;                     // Qs: 128 KB
    const size_t OFF_QKB = OFF_QS + (size_t)B_ * E_ * 4;      // qkb: 512 KB
    const size_t OFF_SG  = OFF_QKB + (size_t)B_ * H_ * E_ * 2; // sg: 1 MB
    float* PPpart = (float*)(ws);
    float* P2p    = (float*)(ws + OFF_P2P);
    float* ssum   = (float*)(ws + OFF_SS);
    float* qb     = (float*)(ws + OFF_QB);
    float* Qs     = (float*)(ws + OFF_QS);
    unsigned short* qkb = (unsigned short*)(ws + OFF_QKB);
    float* sg     = (float*)(ws + OFF_SG);

    // zero atomic-accumulated regions: P2p + ssum + qb (contiguous)
    hipMemsetAsync(ws + OFF_P2P, 0, SZ_P2P + 2048, stream);

    hipLaunchKernelGGL(k_q, dim3(256 + NT_ * B_), dim3(256), 0, stream,
                       query, Wq, bq, bk, Qs, qb, value2, mask, P2p);
    hipLaunchKernelGGL(k_k, dim3(256), dim3(256), 0, stream,
                       Qs, Wk, qkb);
    hipLaunchKernelGGL(k_dots, dim3(NT_, B_), dim3(256), 0, stream,
                       key, qkb, qb, sg, ssum);
    hipLaunchKernelGGL(k_outer, dim3(NT_, B_), dim3(256), 0, stream,
                       key, sg, PPpart);
    hipLaunchKernelGGL(k_tail, dim3(B_ * H_), dim3(512), 0, stream,
                       PPpart, P2p, ssum, mask, Wv, bv, Wb, bb, Wl2, bl2,
                       value1, out);
}

// Round 18
// 356.336 us; speedup vs baseline: 1.0405x; 1.0405x over previous
//
#include <hip/hip_runtime.h>

// Problem dims
#define B_  32
#define N_  1024
#define E_  1024
#define H_  8
#define D_  128
#define MID_ 64
#define NT_  32        // n-tiles for score+pool (32 rows each)
#define NSP_ 32        // v2-pool split rows

// Journal (counter-backed lessons):
//  R3: never replay a stream. R4: never scale same-dest atomic writers.
//  R5/R6: VGPR=64 cap + big live-set = spill; plain launch_bounds only.
//  R7: fp32 scorepool 92us. R9: live-set arithmetic BEFORE benching.
//  R10: interleave degrades both. R11: weight batching NULL.
//  R12: mega-kernel = spill dead end; ~240us/iter is HARNESS-FIXED
//      (512MB re-poison fills @77us + chain). R13: LDS-only barriers NULL.
//  R14: NT=64 NULL. R15: MFMA dots -> k_main ~75, total 353.4 (BEST).
//  R16: key double-buffer (56KB LDS) REGRESSED: 2 blk/CU + L2 aging.
//  R17: dots/outer split REGRESSED (+17us): extra launch + sg round-trip
//      beat the L3 win. R15's fused form is the proven structure.
//  R18: R15 verbatim + T14 async-STAGE split (guide G15): issue quarter
//      q+1's global loads into regs BEFORE the MFMA phase; convert+write
//      after the post-MFMA barrier. No LDS growth (QL staged once, 38KB
//      total, 4 blk/CU), no barrier-count change, peak VGPR unchanged.

typedef __attribute__((ext_vector_type(8))) short bf16x8;
typedef __attribute__((ext_vector_type(4))) float f32x4;

// fp32 -> 2x bf16 packed (round-to-nearest-even)
__device__ __forceinline__ unsigned bf2(float a, float b) {
    unsigned ua = __float_as_uint(a);
    ua = (ua + 0x7fffu + ((ua >> 16) & 1u)) >> 16;
    unsigned ub = __float_as_uint(b);
    ub = (ub + 0x7fffu + ((ub >> 16) & 1u)) >> 16;
    return ua | (ub << 16);
}

// ---------------------------------------------------------------------------
// k_q: blocks [0,256): Qs = query@Wq^T + bq (batched: 8 b x 16 rows/block);
//      blocks [256,1280): v2 pooling (independent stream, overlaps).
// ---------------------------------------------------------------------------
__global__ __launch_bounds__(256) void k_q(
        const float* __restrict__ query, const float* __restrict__ Wq,
        const float* __restrict__ bq, const float* __restrict__ bk,
        float* __restrict__ Qs, float* __restrict__ qb,
        const float* __restrict__ value2, const int* __restrict__ mask,
        float* __restrict__ P2p)
{
    const int t = threadIdx.x;

    __shared__ __align__(16) float qsh[8 * E_];   // 32 KB: 8 query rows
    __shared__ __align__(16) float Qrow[8][16];   // [bb][r]
    __shared__ int rows[NSP_];
    __shared__ int nrows;

    if (blockIdx.x < 256) {
        const int bg = blockIdx.x >> 6;        // 0..3 -> b0 = bg*8
        const int rs = blockIdx.x & 63;        // 0..63 -> rows rs*16
        const int b0 = bg * 8;
        const int R  = rs * 16;
        const int h  = rs >> 3;

        {
            const int bb = t >> 5, ln = t & 31;
            const float4* src = (const float4*)(query + (size_t)(b0 + bb) * E_);
            float4* dst = (float4*)(qsh + bb * E_);
            #pragma unroll
            for (int i = 0; i < 8; ++i) dst[ln + i * 32] = src[ln + i * 32];
        }
        __syncthreads();

        const int r = t >> 4, cl = t & 15;
        const int row = R + r;
        const float4* wr = (const float4*)(Wq + (size_t)row * E_);
        float4 wchunk[16];
        #pragma unroll
        for (int i = 0; i < 16; ++i) wchunk[i] = wr[cl + i * 16];

        const float bqv = bq[row];
        const float4* qsh4 = (const float4*)qsh;
        #pragma unroll
        for (int bb = 0; bb < 8; ++bb) {
            float acc = 0.f;
            #pragma unroll
            for (int i = 0; i < 16; ++i) {
                float4 q = qsh4[bb * 256 + cl + i * 16];
                acc += wchunk[i].x * q.x + wchunk[i].y * q.y
                     + wchunk[i].z * q.z + wchunk[i].w * q.w;
            }
            #pragma unroll
            for (int off = 8; off; off >>= 1) acc += __shfl_xor(acc, off);
            if (cl == 0) Qrow[bb][r] = acc + bqv;
        }
        __syncthreads();

        if (t < 8) {
            float s = 0.f;
            #pragma unroll
            for (int rr = 0; rr < 16; ++rr) s += Qrow[t][rr] * bk[R + rr];
            atomicAdd(&qb[(b0 + t) * 8 + h], s);
        }
        if (t < 32) {
            const int bb = t >> 2, j = t & 3;
            ((float4*)(Qs + (size_t)(b0 + bb) * E_))[rs * 4 + j] =
                *(const float4*)&Qrow[bb][j * 4];
        }
    } else {
        // ---- v2 pooling: 32-row split; P2p[sp&7] partials
        const int pi = blockIdx.x - 256;        // [0,1024)
        const int b = pi & 31, sp = pi >> 5;
        const int e0 = t * 4;
        const int n0 = sp * NSP_;

        if (t == 0) nrows = 0;
        __syncthreads();
        if (t < NSP_) {
            if (mask[b * N_ + n0 + t]) {
                int i2 = atomicAdd(&nrows, 1);
                rows[i2] = t;
            }
        }
        __syncthreads();
        const int nr = nrows;

        float a0 = 0.f, a1 = 0.f, a2 = 0.f, a3 = 0.f;
        const float* vb = value2 + ((size_t)(b * N_ + n0)) * E_ + e0;
        #pragma unroll 4
        for (int i = 0; i < nr; ++i) {
            float4 v = *(const float4*)(vb + (size_t)rows[i] * E_);
            a0 += v.x; a1 += v.y; a2 += v.z; a3 += v.w;
        }
        float* dst = P2p + ((size_t)(sp & 7) * B_ + b) * E_ + e0;
        atomicAdd(dst + 0, a0); atomicAdd(dst + 1, a1);
        atomicAdd(dst + 2, a2); atomicAdd(dst + 3, a3);
    }
}

// ---------------------------------------------------------------------------
// k_k: qkb[b,h,e] (bf16) = sum_d Qs[b,h*D+d] * Wk[h*D+d,e], LDS-tiled GEMM.
// ---------------------------------------------------------------------------
__global__ __launch_bounds__(256) void k_k(
        const float* __restrict__ Qs, const float* __restrict__ Wk,
        unsigned short* __restrict__ qkb)
{
    const int h = blockIdx.x >> 5, ec = blockIdx.x & 31;
    const int t = threadIdx.x;

    __shared__ __align__(16) float QsL[32 * 132];   // padded, 16.9 KB
    __shared__ __align__(16) float WkL[128 * 32];   // 16 KB

    {
        const int b = t >> 3, j = t & 7;
        const float4* src = (const float4*)(Qs + (size_t)b * E_) + h * 32;
        float4* dst = (float4*)(QsL + b * 132);
        #pragma unroll
        for (int jj = 0; jj < 4; ++jj) dst[j + jj * 8] = src[j + jj * 8];
    }
    {
        #pragma unroll
        for (int jj = 0; jj < 4; ++jj) {
            const int idx = t + jj * 256;
            const int d = idx >> 3, c = idx & 7;
            ((float4*)WkL)[idx] =
                ((const float4*)(Wk + (size_t)(h * D_ + d) * E_))[ec * 8 + c];
        }
    }
    __syncthreads();

    const int b = t >> 3, eg = t & 7;
    float4 acc = make_float4(0.f, 0.f, 0.f, 0.f);
    const float* q = QsL + b * 132;
    const float4* wk4 = (const float4*)WkL;
    #pragma unroll 8
    for (int d = 0; d < D_; ++d) {
        float qd = q[d];
        float4 w = wk4[d * 8 + eg];
        acc.x += qd * w.x; acc.y += qd * w.y;
        acc.z += qd * w.z; acc.w += qd * w.w;
    }
    uint2 pk;
    pk.x = bf2(acc.x, acc.y);
    pk.y = bf2(acc.z, acc.w);
    ((uint2*)(qkb + (size_t)(b * 8 + h) * E_))[ec * 8 + eg] = pk;
}

// ---------------------------------------------------------------------------
// k_main (R15 fused + T14 async-STAGE): per (tile,b), 32-row tiles.
//   QL staged once (16.5 KB). Key quarters single-buffered (16.5 KB), but
//   quarter q+1's global loads issue into kf regs BEFORE the MFMAs on q;
//   convert+ds_write happen after the post-MFMA barrier (vmcnt wait lands
//   there, covered by MFMA + barrier-wait). LDS 38 KB -> 4 blk/CU.
//   Outer pass = R7's fp32 VALU outer (global re-read, L2-hot), unchanged.
// grid (NT_, B_) = 1024 blocks, 256 thr.
// ---------------------------------------------------------------------------
__global__ __launch_bounds__(256) void k_main(
        const float* __restrict__ key, const unsigned short* __restrict__ qkb,
        const float* __restrict__ qb, float* __restrict__ PPpart,
        float* __restrict__ ssum)
{
    const int tile = blockIdx.x, b = blockIdx.y;
    const int t = threadIdx.x;
    const int w = t >> 6, l = t & 63;

    __shared__ __align__(16) unsigned short KLs[32 * 264];   // 16.5 KB
    __shared__ __align__(16) unsigned short QLs[8 * 1032];   // 16.5 KB
    __shared__ __align__(16) float part[2][2][16][16];       // 4 KB
    __shared__ __align__(16) float sfin[32][8];              // 1 KB

    const float scale = 0.08838834764831845f;  // 1/sqrt(128)
    const float* keyb = key + ((size_t)b * N_ + (size_t)tile * 32) * E_;
    const unsigned short* qkbb = qkb + (size_t)(b * 8) * E_;

    const int mtile = w & 1, ksub = w >> 1;
    const int arow = mtile * 16 + (l & 15);
    const int brow = l & 7;                 // cols>=8 duplicate valid data
    const int kgrp = (l >> 4) * 16;         // byte offset of lane's k-group

    // per-thread stage coords (8 elements: idx = t + j*256)
    // row = idx>>6, c4 = idx&63
    f32x4 Cacc = {0.f, 0.f, 0.f, 0.f};

    // stage QL once: 8 h x 1024 bf16 (2048 uint2, 8 per thread), coalesced
    #pragma unroll
    for (int j = 0; j < 8; ++j) {
        const int idx = t + j * 256;
        const int h = idx >> 8, c4 = idx & 255;
        ((uint2*)(QLs + h * 1032))[c4] =
            ((const uint2*)(qkbb + (size_t)h * E_))[c4];
    }
    // prologue: quarter 0 -> regs -> convert -> LDS
    float4 kf[8];
    #pragma unroll
    for (int j = 0; j < 8; ++j) {
        const int idx = t + j * 256;
        kf[j] = ((const float4*)(keyb + (size_t)(idx >> 6) * E_))[idx & 63];
    }
    #pragma unroll
    for (int j = 0; j < 8; ++j) {
        const int idx = t + j * 256;
        uint2 pk;
        pk.x = bf2(kf[j].x, kf[j].y);
        pk.y = bf2(kf[j].z, kf[j].w);
        ((uint2*)(KLs + (idx >> 6) * 264))[idx & 63] = pk;
    }
    __syncthreads();

    #pragma unroll
    for (int q = 0; q < 4; ++q) {
        // T14 issue-early: quarter q+1's global loads go in flight NOW,
        // before the MFMA phase; they complete during MFMA + barrier-wait.
        if (q < 3) {
            #pragma unroll
            for (int j = 0; j < 8; ++j) {
                const int idx = t + j * 256;
                kf[j] = ((const float4*)(keyb
                            + (size_t)(idx >> 6) * E_))[(q + 1) * 64 + (idx & 63)];
            }
        }
        // 4 MFMA k-steps on KLs (B from QL panel at byte offset q*512)
        #pragma unroll
        for (int s = 0; s < 4; ++s) {
            const int koff = (ksub * 4 + s) * 64 + kgrp;          // bytes
            const int qoff = q * 512 + koff;                      // bytes
            bf16x8 a  = *(const bf16x8*)((const char*)(KLs + arow * 264) + koff);
            bf16x8 bb = *(const bf16x8*)((const char*)(QLs + brow * 1032) + qoff);
            Cacc = __builtin_amdgcn_mfma_f32_16x16x32_bf16(a, bb, Cacc, 0, 0, 0);
        }
        if (q < 3) {
            __syncthreads();   // all waves done READING KLs quarter q
            // write-late: vmcnt wait on kf lands here (mostly covered)
            #pragma unroll
            for (int j = 0; j < 8; ++j) {
                const int idx = t + j * 256;
                uint2 pk;
                pk.x = bf2(kf[j].x, kf[j].y);
                pk.y = bf2(kf[j].z, kf[j].w);
                ((uint2*)(KLs + (idx >> 6) * 264))[idx & 63] = pk;
            }
            __syncthreads();   // writes visible before next MFMA
        }
    }

    // write C partials: lane l holds S[(l>>4)*4+j][l&15] for its (mtile,ksub)
    #pragma unroll
    for (int j = 0; j < 4; ++j)
        part[mtile][ksub][(l >> 4) * 4 + j][l & 15] = Cacc[j];
    __syncthreads();

    // finalize s: thread (r = t>>3, h = t&7)
    {
        const int r = t >> 3, h = t & 7;
        const float s = (part[r >> 4][0][r & 15][h]
                       + part[r >> 4][1][r & 15][h]
                       + qb[b * 8 + h]) * scale;
        sfin[r][h] = s;
    }
    __syncthreads();

    if (t < 8) {
        float ts = 0.f;
        #pragma unroll
        for (int r = 0; r < 32; ++r) ts += sfin[r][t];
        atomicAdd(&ssum[b * 8 + t], ts);
    }

    // outer pass: PP[h,e] += s[n,h]*K[n,e]; rows re-read from global (L2-hot)
    float4 pacc[8];
    #pragma unroll
    for (int h = 0; h < 8; ++h) pacc[h] = make_float4(0.f, 0.f, 0.f, 0.f);

    float4 kv[4];
    #pragma unroll
    for (int r = 0; r < 4; ++r)
        kv[r] = ((const float4*)(keyb + (size_t)r * E_))[t];

    for (int st = 0; st < 8; ++st) {
        float4 kn[4];
        if (st < 7) {
            #pragma unroll
            for (int r = 0; r < 4; ++r)
                kn[r] = ((const float4*)(keyb
                            + (size_t)((st + 1) * 4 + r) * E_))[t];
        }
        #pragma unroll
        for (int r = 0; r < 4; ++r) {
            const float4 k4 = kv[r];
            const float4 sA = *(const float4*)&sfin[st * 4 + r][0];
            const float4 sB = *(const float4*)&sfin[st * 4 + r][4];
            pacc[0].x += sA.x * k4.x; pacc[0].y += sA.x * k4.y;
            pacc[0].z += sA.x * k4.z; pacc[0].w += sA.x * k4.w;
            pacc[1].x += sA.y * k4.x; pacc[1].y += sA.y * k4.y;
            pacc[1].z += sA.y * k4.z; pacc[1].w += sA.y * k4.w;
            pacc[2].x += sA.z * k4.x; pacc[2].y += sA.z * k4.y;
            pacc[2].z += sA.z * k4.z; pacc[2].w += sA.z * k4.w;
            pacc[3].x += sA.w * k4.x; pacc[3].y += sA.w * k4.y;
            pacc[3].z += sA.w * k4.z; pacc[3].w += sA.w * k4.w;
            pacc[4].x += sB.x * k4.x; pacc[4].y += sB.x * k4.y;
            pacc[4].z += sB.x * k4.z; pacc[4].w += sB.x * k4.w;
            pacc[5].x += sB.y * k4.x; pacc[5].y += sB.y * k4.y;
            pacc[5].z += sB.y * k4.z; pacc[5].w += sB.y * k4.w;
            pacc[6].x += sB.z * k4.x; pacc[6].y += sB.z * k4.y;
            pacc[6].z += sB.z * k4.z; pacc[6].w += sB.z * k4.w;
            pacc[7].x += sB.w * k4.x; pacc[7].y += sB.w * k4.y;
            pacc[7].z += sB.w * k4.z; pacc[7].w += sB.w * k4.w;
        }
        #pragma unroll
        for (int r = 0; r < 4; ++r) kv[r] = kn[r];
    }

    #pragma unroll
    for (int h = 0; h < 8; ++h) {
        ((float4*)(PPpart
            + (((size_t)(b * H_ + h)) * NT_ + tile) * E_))[t] = pacc[h];
    }
}

// ---------------------------------------------------------------------------
// k_tail: per bh, 512 threads. reduce + Wv dots + epilogue (R13-proven).
// ---------------------------------------------------------------------------
__global__ __launch_bounds__(512) void k_tail(
        const float* __restrict__ PPpart, const float* __restrict__ P2p,
        const float* __restrict__ ssumg, const int* __restrict__ mask,
        const float* __restrict__ Wv, const float* __restrict__ bv,
        const float* __restrict__ Wb, const float* __restrict__ bb,
        const float* __restrict__ Wl2, const float* __restrict__ bl2,
        const float* __restrict__ value1, float* __restrict__ out)
{
    const int bh = blockIdx.x, b = bh >> 3, h = bh & 7;
    const int t = threadIdx.x;
    const int l = t & 63, w = t >> 6;       // 8 waves
    const int rg = l >> 4, cl = l & 15;     // 4 row-groups x 16 lanes

    __shared__ __align__(16) float ph[2][E_];
    __shared__ __align__(16) float pooled[E_];
    __shared__ __align__(16) float pool2[E_];
    __shared__ float attA_s[D_];
    __shared__ float attV_s[D_];
    __shared__ float att[D_];
    __shared__ float hv[MID_];
    __shared__ float red2[2];
    __shared__ float cnt_s;

    {
        const int c4 = t & 255, half = t >> 8;
        const float4* pp = (const float4*)(PPpart + (size_t)bh * NT_ * E_);
        float4 s = make_float4(0.f, 0.f, 0.f, 0.f);
        #pragma unroll 4
        for (int j = 0; j < 16; ++j) {
            float4 v = pp[(half * 16 + j) * 256 + c4];
            s.x += v.x; s.y += v.y; s.z += v.z; s.w += v.w;
        }
        ((float4*)&ph[half][0])[c4] = s;
    }
    __syncthreads();
    if (t < 256) {
        float4 p0 = ((const float4*)&ph[0][0])[t];
        float4 p1 = ((const float4*)&ph[1][0])[t];
        ((float4*)pooled)[t] = make_float4(p0.x + p1.x, p0.y + p1.y,
                                           p0.z + p1.z, p0.w + p1.w);
        float4 q = make_float4(0.f, 0.f, 0.f, 0.f);
        #pragma unroll
        for (int k2 = 0; k2 < 8; ++k2) {
            float4 v = ((const float4*)(P2p + ((size_t)k2 * B_ + b) * E_))[t];
            q.x += v.x; q.y += v.y; q.z += v.z; q.w += v.w;
        }
        ((float4*)pool2)[t] = q;
    }
    __syncthreads();

    const float4* pooled4 = (const float4*)pooled;
    const float4* pool24  = (const float4*)pool2;
    #pragma unroll
    for (int p = 0; p < 4; ++p) {
        const int d = p * 32 + w * 4 + rg;
        const float4* wvr = (const float4*)(Wv + (size_t)(h * D_ + d) * E_);
        float pA = 0.f, pV = 0.f;
        #pragma unroll 4
        for (int i = 0; i < 16; ++i) {
            float4 wv4 = wvr[cl + i * 16];
            float4 pa = pooled4[cl + i * 16];
            float4 pb = pool24[cl + i * 16];
            pA += wv4.x * pa.x + wv4.y * pa.y + wv4.z * pa.z + wv4.w * pa.w;
            pV += wv4.x * pb.x + wv4.y * pb.y + wv4.z * pb.z + wv4.w * pb.w;
        }
        #pragma unroll
        for (int off = 8; off; off >>= 1) {
            pA += __shfl_xor(pA, off);
            pV += __shfl_xor(pV, off);
        }
        if (cl == 0) { attA_s[d] = pA; attV_s[d] = pV; }
    }
    __syncthreads();

    if (t < 128) {
        int ci = 0;
        #pragma unroll
        for (int i = 0; i < 8; ++i) ci += mask[b * N_ + t + i * 128];
        float cf = (float)ci;
        #pragma unroll
        for (int off = 32; off; off >>= 1) cf += __shfl_down(cf, off);
        if ((t & 63) == 0) red2[t >> 6] = cf;
        const float ss = ssumg[bh];
        att[t] = attA_s[t] + ss * bv[h * D_ + t];
    }
    __syncthreads();
    if (t == 0) cnt_s = red2[0] + red2[1];
    if (t < MID_) {
        float a = bb[t];
        #pragma unroll 4
        for (int d2 = 0; d2 < D_; ++d2) a += att[d2] * Wb[t * D_ + d2];
        hv[t] = fmaxf(a, 0.f);
    }
    __syncthreads();
    if (t < 128) {
        float z = bl2[t];
        #pragma unroll
        for (int m = 0; m < MID_; ++m) z += hv[m] * Wl2[t * MID_ + m];
        float alphac = 1.f / (1.f + expf(-z));
        const float bvd = bv[h * D_ + t];
        float v2a = attV_s[t] / cnt_s + bvd;
        out[(size_t)b * E_ + h * D_ + t] =
            value1[(size_t)b * E_ + h * D_ + t] * v2a * alphac;
    }
}

// ---------------------------------------------------------------------------
extern "C" void kernel_launch(void* const* d_in, const int* in_sizes, int n_in,
                              void* d_out, int out_size, void* d_ws, size_t ws_size,
                              hipStream_t stream)
{
    const float* query  = (const float*)d_in[0];
    const float* key    = (const float*)d_in[1];
    const int*   mask   = (const int*)d_in[2];
    const float* value1 = (const float*)d_in[3];
    const float* value2 = (const float*)d_in[4];
    const float* Wq  = (const float*)d_in[5];
    const float* bq  = (const float*)d_in[6];
    const float* Wk  = (const float*)d_in[7];
    const float* bk  = (const float*)d_in[8];
    const float* Wv  = (const float*)d_in[9];
    const float* bv  = (const float*)d_in[10];
    const float* Wb  = (const float*)d_in[11];
    const float* bb  = (const float*)d_in[12];
    // d_in[13] = Wl, d_in[14] = bl: eliminated (softmax of uniform = mask/cnt)
    const float* Wl2 = (const float*)d_in[15];
    const float* bl2 = (const float*)d_in[16];
    float* out = (float*)d_out;

    // workspace layout (bytes), ~35 MB
    char* ws = (char*)d_ws;
    const size_t SZ_PPP = (size_t)B_ * H_ * NT_ * E_ * 4;     // PPpart: 32 MB
    const size_t SZ_P2P = (size_t)8 * B_ * E_ * 4;            // P2p: 1 MB
    const size_t OFF_P2P = SZ_PPP;
    const size_t OFF_SS  = OFF_P2P + SZ_P2P;                  // ssum: 1 KB
    const size_t OFF_QB  = OFF_SS + 1024;                     // qb: 1 KB
    const size_t OFF_QS  = OFF_QB + 1024;                     // Qs: 128 KB
    const size_t OFF_QKB = OFF_QS + (size_t)B_ * E_ * 4;      // qkb: 512 KB
    float* PPpart = (float*)(ws);
    float* P2p    = (float*)(ws + OFF_P2P);
    float* ssum   = (float*)(ws + OFF_SS);
    float* qb     = (float*)(ws + OFF_QB);
    float* Qs     = (float*)(ws + OFF_QS);
    unsigned short* qkb = (unsigned short*)(ws + OFF_QKB);

    // zero atomic-accumulated regions: P2p + ssum + qb (contiguous)
    hipMemsetAsync(ws + OFF_P2P, 0, SZ_P2P + 2048, stream);

    hipLaunchKernelGGL(k_q, dim3(256 + NT_ * B_), dim3(256), 0, stream,
                       query, Wq, bq, bk, Qs, qb, value2, mask, P2p);
    hipLaunchKernelGGL(k_k, dim3(256), dim3(256), 0, stream,
                       Qs, Wk, qkb);
    hipLaunchKernelGGL(k_main, dim3(NT_, B_), dim3(256), 0, stream,
                       key, qkb, qb, PPpart, ssum);
    hipLaunchKernelGGL(k_tail, dim3(B_ * H_), dim3(512), 0, stream,
                       PPpart, P2p, ssum, mask, Wv, bv, Wb, bb, Wl2, bl2,
                       value1, out);
}

// Round 19
// 353.260 us; speedup vs baseline: 1.0495x; 1.0087x over previous
//
#include <hip/hip_runtime.h>

// Problem dims
#define B_  32
#define N_  1024
#define E_  1024
#define H_  8
#define D_  128
#define MID_ 64
#define NT_  32        // n-tiles for score+pool (32 rows each)
#define NSP_ 32        // v2-pool split rows

// Journal (counter-backed lessons) — FINAL:
//  R3: never replay a stream. R4: never scale same-dest atomic writers.
//  R5/R6: VGPR=64 cap + big live-set = spill; plain launch_bounds only.
//  R7: fp32 scorepool 92us. R9: live-set arithmetic BEFORE benching.
//  R10: interleaving a barrier-heavy kernel with a streaming kernel
//      degrades both. R11: weight batching NULL. R12: mega-kernel = spill
//      dead end; ~240us/iter is HARNESS-FIXED (512MB re-poison fills run
//      at 86% HBM peak + reset chain — counter-proven, uncontrollable).
//  R13: LDS-only barriers NULL. R14: NT=64 NULL.
//  R15: MFMA dots (16x16x32 bf16) replace the shfl-reduce: k_main 92->~75,
//      total 353.4 = SESSION BEST. absmax 4.9e-4 (bf16 scores), 40x under
//      the 2% threshold.
//  R16: key double-buffer REGRESSED (LDS 56KB -> 2 blk/CU + L2 aging).
//  R17: dots/outer split REGRESSED (+17us). R18: T14 async-stage NULL.
//  => R19: R15 restored verbatim. Controllable kernel sum ~113us vs ~90us
//     realistic floor; every catalog lever A/B'd (occupancy, barriers,
//     pipelining, splitting, MFMA, stream overlap). Terminal submission.

typedef __attribute__((ext_vector_type(8))) short bf16x8;
typedef __attribute__((ext_vector_type(4))) float f32x4;

// fp32 -> 2x bf16 packed (round-to-nearest-even)
__device__ __forceinline__ unsigned bf2(float a, float b) {
    unsigned ua = __float_as_uint(a);
    ua = (ua + 0x7fffu + ((ua >> 16) & 1u)) >> 16;
    unsigned ub = __float_as_uint(b);
    ub = (ub + 0x7fffu + ((ub >> 16) & 1u)) >> 16;
    return ua | (ub << 16);
}

// ---------------------------------------------------------------------------
// k_q: blocks [0,256): Qs = query@Wq^T + bq (batched: 8 b x 16 rows/block);
//      blocks [256,1280): v2 pooling (independent stream, overlaps).
// ---------------------------------------------------------------------------
__global__ __launch_bounds__(256) void k_q(
        const float* __restrict__ query, const float* __restrict__ Wq,
        const float* __restrict__ bq, const float* __restrict__ bk,
        float* __restrict__ Qs, float* __restrict__ qb,
        const float* __restrict__ value2, const int* __restrict__ mask,
        float* __restrict__ P2p)
{
    const int t = threadIdx.x;

    __shared__ __align__(16) float qsh[8 * E_];   // 32 KB: 8 query rows
    __shared__ __align__(16) float Qrow[8][16];   // [bb][r]
    __shared__ int rows[NSP_];
    __shared__ int nrows;

    if (blockIdx.x < 256) {
        const int bg = blockIdx.x >> 6;        // 0..3 -> b0 = bg*8
        const int rs = blockIdx.x & 63;        // 0..63 -> rows rs*16
        const int b0 = bg * 8;
        const int R  = rs * 16;
        const int h  = rs >> 3;

        {
            const int bb = t >> 5, ln = t & 31;
            const float4* src = (const float4*)(query + (size_t)(b0 + bb) * E_);
            float4* dst = (float4*)(qsh + bb * E_);
            #pragma unroll
            for (int i = 0; i < 8; ++i) dst[ln + i * 32] = src[ln + i * 32];
        }
        __syncthreads();

        const int r = t >> 4, cl = t & 15;
        const int row = R + r;
        const float4* wr = (const float4*)(Wq + (size_t)row * E_);
        float4 wchunk[16];
        #pragma unroll
        for (int i = 0; i < 16; ++i) wchunk[i] = wr[cl + i * 16];

        const float bqv = bq[row];
        const float4* qsh4 = (const float4*)qsh;
        #pragma unroll
        for (int bb = 0; bb < 8; ++bb) {
            float acc = 0.f;
            #pragma unroll
            for (int i = 0; i < 16; ++i) {
                float4 q = qsh4[bb * 256 + cl + i * 16];
                acc += wchunk[i].x * q.x + wchunk[i].y * q.y
                     + wchunk[i].z * q.z + wchunk[i].w * q.w;
            }
            #pragma unroll
            for (int off = 8; off; off >>= 1) acc += __shfl_xor(acc, off);
            if (cl == 0) Qrow[bb][r] = acc + bqv;
        }
        __syncthreads();

        if (t < 8) {
            float s = 0.f;
            #pragma unroll
            for (int rr = 0; rr < 16; ++rr) s += Qrow[t][rr] * bk[R + rr];
            atomicAdd(&qb[(b0 + t) * 8 + h], s);
        }
        if (t < 32) {
            const int bb = t >> 2, j = t & 3;
            ((float4*)(Qs + (size_t)(b0 + bb) * E_))[rs * 4 + j] =
                *(const float4*)&Qrow[bb][j * 4];
        }
    } else {
        // ---- v2 pooling: 32-row split; P2p[sp&7] partials
        const int pi = blockIdx.x - 256;        // [0,1024)
        const int b = pi & 31, sp = pi >> 5;
        const int e0 = t * 4;
        const int n0 = sp * NSP_;

        if (t == 0) nrows = 0;
        __syncthreads();
        if (t < NSP_) {
            if (mask[b * N_ + n0 + t]) {
                int i2 = atomicAdd(&nrows, 1);
                rows[i2] = t;
            }
        }
        __syncthreads();
        const int nr = nrows;

        float a0 = 0.f, a1 = 0.f, a2 = 0.f, a3 = 0.f;
        const float* vb = value2 + ((size_t)(b * N_ + n0)) * E_ + e0;
        #pragma unroll 4
        for (int i = 0; i < nr; ++i) {
            float4 v = *(const float4*)(vb + (size_t)rows[i] * E_);
            a0 += v.x; a1 += v.y; a2 += v.z; a3 += v.w;
        }
        float* dst = P2p + ((size_t)(sp & 7) * B_ + b) * E_ + e0;
        atomicAdd(dst + 0, a0); atomicAdd(dst + 1, a1);
        atomicAdd(dst + 2, a2); atomicAdd(dst + 3, a3);
    }
}

// ---------------------------------------------------------------------------
// k_k: qkb[b,h,e] (bf16) = sum_d Qs[b,h*D+d] * Wk[h*D+d,e], LDS-tiled GEMM.
// fp32 compute, bf16 packed store (k_main's MFMA B-operand).
// ---------------------------------------------------------------------------
__global__ __launch_bounds__(256) void k_k(
        const float* __restrict__ Qs, const float* __restrict__ Wk,
        unsigned short* __restrict__ qkb)
{
    const int h = blockIdx.x >> 5, ec = blockIdx.x & 31;
    const int t = threadIdx.x;

    __shared__ __align__(16) float QsL[32 * 132];   // padded, 16.9 KB
    __shared__ __align__(16) float WkL[128 * 32];   // 16 KB

    {
        const int b = t >> 3, j = t & 7;
        const float4* src = (const float4*)(Qs + (size_t)b * E_) + h * 32;
        float4* dst = (float4*)(QsL + b * 132);
        #pragma unroll
        for (int jj = 0; jj < 4; ++jj) dst[j + jj * 8] = src[j + jj * 8];
    }
    {
        #pragma unroll
        for (int jj = 0; jj < 4; ++jj) {
            const int idx = t + jj * 256;
            const int d = idx >> 3, c = idx & 7;
            ((float4*)WkL)[idx] =
                ((const float4*)(Wk + (size_t)(h * D_ + d) * E_))[ec * 8 + c];
        }
    }
    __syncthreads();

    const int b = t >> 3, eg = t & 7;
    float4 acc = make_float4(0.f, 0.f, 0.f, 0.f);
    const float* q = QsL + b * 132;
    const float4* wk4 = (const float4*)WkL;
    #pragma unroll 8
    for (int d = 0; d < D_; ++d) {
        float qd = q[d];
        float4 w = wk4[d * 8 + eg];
        acc.x += qd * w.x; acc.y += qd * w.y;
        acc.z += qd * w.z; acc.w += qd * w.w;
    }
    uint2 pk;
    pk.x = bf2(acc.x, acc.y);
    pk.y = bf2(acc.z, acc.w);
    ((uint2*)(qkb + (size_t)(b * 8 + h) * E_))[ec * 8 + eg] = pk;
}

// ---------------------------------------------------------------------------
// k_main (MFMA dots, R15-proven): per (tile,b), 32-row tiles.
//   4 e-quarters: stage key(bf16,LDS pad-264) + qkb slice -> 4 waves x 4
//   mfma_f32_16x16x32_bf16, C accumulated in regs across quarters.
//   No shuffles anywhere. Finalize s via part[] combine; outer pass = R7's
//   fp32 outer (global re-read, L2-hot), barrier-free.
// grid (NT_, B_) = 1024 blocks, 256 thr, ~26 KB LDS.
// ---------------------------------------------------------------------------
__global__ __launch_bounds__(256) void k_main(
        const float* __restrict__ key, const unsigned short* __restrict__ qkb,
        const float* __restrict__ qb, float* __restrict__ PPpart,
        float* __restrict__ ssum)
{
    const int tile = blockIdx.x, b = blockIdx.y;
    const int t = threadIdx.x;
    const int w = t >> 6, l = t & 63;

    __shared__ __align__(16) unsigned short KLs[32 * 264];  // 16.5 KB
    __shared__ __align__(16) unsigned short QLs[8 * 264];   // 4.1 KB
    __shared__ __align__(16) float part[2][2][16][16];      // 4 KB
    __shared__ __align__(16) float sfin[32][8];             // 1 KB

    const float scale = 0.08838834764831845f;  // 1/sqrt(128)
    const float* keyb = key + ((size_t)b * N_ + (size_t)tile * 32) * E_;
    const unsigned short* qkbb = qkb + (size_t)(b * 8) * E_;

    const int mtile = w & 1, ksub = w >> 1;
    const int arow = mtile * 16 + (l & 15);
    const int brow = l & 7;                 // cols>=8 duplicate valid data
    const int kgrp = (l >> 4) * 16;         // byte offset of lane's k-group

    f32x4 Cacc = {0.f, 0.f, 0.f, 0.f};

    for (int q = 0; q < 4; ++q) {
        // stage key quarter: 32 rows x 256 floats -> bf16 (coalesced)
        #pragma unroll
        for (int j = 0; j < 8; ++j) {
            const int idx = t + j * 256;
            const int row = idx >> 6, c4 = idx & 63;
            float4 v = ((const float4*)(keyb + (size_t)row * E_))[q * 64 + c4];
            uint2 pk;
            pk.x = bf2(v.x, v.y);
            pk.y = bf2(v.z, v.w);
            ((uint2*)(KLs + row * 264))[c4] = pk;
        }
        // stage qk quarter: 8 h x 256 bf16
        #pragma unroll
        for (int j = 0; j < 2; ++j) {
            const int idx = t + j * 256;
            const int h = idx >> 6, c4 = idx & 63;
            ((uint2*)(QLs + h * 264))[c4] =
                ((const uint2*)(qkbb + (size_t)h * E_))[q * 64 + c4];
        }
        __syncthreads();
        // 4 MFMA k-steps for this wave (k = q*256 + (ksub*4+s)*32 + lane k-grp)
        #pragma unroll
        for (int s = 0; s < 4; ++s) {
            const int koff = (ksub * 4 + s) * 64 + kgrp;   // bytes
            bf16x8 a = *(const bf16x8*)((const char*)(KLs + arow * 264) + koff);
            bf16x8 bb = *(const bf16x8*)((const char*)(QLs + brow * 264) + koff);
            Cacc = __builtin_amdgcn_mfma_f32_16x16x32_bf16(a, bb, Cacc, 0, 0, 0);
        }
        if (q < 3) __syncthreads();   // before restaging KLs/QLs
    }

    // write C partials: lane l holds S[(l>>4)*4+j][l&15] for its (mtile,ksub)
    #pragma unroll
    for (int j = 0; j < 4; ++j)
        part[mtile][ksub][(l >> 4) * 4 + j][l & 15] = Cacc[j];
    __syncthreads();

    // finalize s: thread (r = t>>3, h = t&7)
    {
        const int r = t >> 3, h = t & 7;
        const float s = (part[r >> 4][0][r & 15][h]
                       + part[r >> 4][1][r & 15][h]
                       + qb[b * 8 + h]) * scale;
        sfin[r][h] = s;
    }
    __syncthreads();

    if (t < 8) {
        float ts = 0.f;
        #pragma unroll
        for (int r = 0; r < 32; ++r) ts += sfin[r][t];
        atomicAdd(&ssum[b * 8 + t], ts);
    }

    // outer pass: PP[h,e] += s[n,h]*K[n,e]; rows re-read from global (L2-hot,
    // 16 resident tiles x 128KB = 2MB < 4MB L2/XCD). No barriers (sfin RO).
    float4 pacc[8];
    #pragma unroll
    for (int h = 0; h < 8; ++h) pacc[h] = make_float4(0.f, 0.f, 0.f, 0.f);

    float4 kv[4];
    #pragma unroll
    for (int r = 0; r < 4; ++r)
        kv[r] = ((const float4*)(keyb + (size_t)r * E_))[t];

    for (int st = 0; st < 8; ++st) {
        float4 kn[4];
        if (st < 7) {
            #pragma unroll
            for (int r = 0; r < 4; ++r)
                kn[r] = ((const float4*)(keyb
                            + (size_t)((st + 1) * 4 + r) * E_))[t];
        }
        #pragma unroll
        for (int r = 0; r < 4; ++r) {
            const float4 k4 = kv[r];
            const float4 sA = *(const float4*)&sfin[st * 4 + r][0];
            const float4 sB = *(const float4*)&sfin[st * 4 + r][4];
            pacc[0].x += sA.x * k4.x; pacc[0].y += sA.x * k4.y;
            pacc[0].z += sA.x * k4.z; pacc[0].w += sA.x * k4.w;
            pacc[1].x += sA.y * k4.x; pacc[1].y += sA.y * k4.y;
            pacc[1].z += sA.y * k4.z; pacc[1].w += sA.y * k4.w;
            pacc[2].x += sA.z * k4.x; pacc[2].y += sA.z * k4.y;
            pacc[2].z += sA.z * k4.z; pacc[2].w += sA.z * k4.w;
            pacc[3].x += sA.w * k4.x; pacc[3].y += sA.w * k4.y;
            pacc[3].z += sA.w * k4.z; pacc[3].w += sA.w * k4.w;
            pacc[4].x += sB.x * k4.x; pacc[4].y += sB.x * k4.y;
            pacc[4].z += sB.x * k4.z; pacc[4].w += sB.x * k4.w;
            pacc[5].x += sB.y * k4.x; pacc[5].y += sB.y * k4.y;
            pacc[5].z += sB.y * k4.z; pacc[5].w += sB.y * k4.w;
            pacc[6].x += sB.z * k4.x; pacc[6].y += sB.z * k4.y;
            pacc[6].z += sB.z * k4.z; pacc[6].w += sB.z * k4.w;
            pacc[7].x += sB.w * k4.x; pacc[7].y += sB.w * k4.y;
            pacc[7].z += sB.w * k4.z; pacc[7].w += sB.w * k4.w;
        }
        #pragma unroll
        for (int r = 0; r < 4; ++r) kv[r] = kn[r];
    }

    #pragma unroll
    for (int h = 0; h < 8; ++h) {
        ((float4*)(PPpart
            + (((size_t)(b * H_ + h)) * NT_ + tile) * E_))[t] = pacc[h];
    }
}

// ---------------------------------------------------------------------------
// k_tail: per bh, 512 threads. reduce + Wv dots + epilogue (R13-proven).
// ---------------------------------------------------------------------------
__global__ __launch_bounds__(512) void k_tail(
        const float* __restrict__ PPpart, const float* __restrict__ P2p,
        const float* __restrict__ ssumg, const int* __restrict__ mask,
        const float* __restrict__ Wv, const float* __restrict__ bv,
        const float* __restrict__ Wb, const float* __restrict__ bb,
        const float* __restrict__ Wl2, const float* __restrict__ bl2,
        const float* __restrict__ value1, float* __restrict__ out)
{
    const int bh = blockIdx.x, b = bh >> 3, h = bh & 7;
    const int t = threadIdx.x;
    const int l = t & 63, w = t >> 6;       // 8 waves
    const int rg = l >> 4, cl = l & 15;     // 4 row-groups x 16 lanes

    __shared__ __align__(16) float ph[2][E_];
    __shared__ __align__(16) float pooled[E_];
    __shared__ __align__(16) float pool2[E_];
    __shared__ float attA_s[D_];
    __shared__ float attV_s[D_];
    __shared__ float att[D_];
    __shared__ float hv[MID_];
    __shared__ float red2[2];
    __shared__ float cnt_s;

    {
        const int c4 = t & 255, half = t >> 8;
        const float4* pp = (const float4*)(PPpart + (size_t)bh * NT_ * E_);
        float4 s = make_float4(0.f, 0.f, 0.f, 0.f);
        #pragma unroll 4
        for (int j = 0; j < 16; ++j) {
            float4 v = pp[(half * 16 + j) * 256 + c4];
            s.x += v.x; s.y += v.y; s.z += v.z; s.w += v.w;
        }
        ((float4*)&ph[half][0])[c4] = s;
    }
    __syncthreads();
    if (t < 256) {
        float4 p0 = ((const float4*)&ph[0][0])[t];
        float4 p1 = ((const float4*)&ph[1][0])[t];
        ((float4*)pooled)[t] = make_float4(p0.x + p1.x, p0.y + p1.y,
                                           p0.z + p1.z, p0.w + p1.w);
        float4 q = make_float4(0.f, 0.f, 0.f, 0.f);
        #pragma unroll
        for (int k2 = 0; k2 < 8; ++k2) {
            float4 v = ((const float4*)(P2p + ((size_t)k2 * B_ + b) * E_))[t];
            q.x += v.x; q.y += v.y; q.z += v.z; q.w += v.w;
        }
        ((float4*)pool2)[t] = q;
    }
    __syncthreads();

    const float4* pooled4 = (const float4*)pooled;
    const float4* pool24  = (const float4*)pool2;
    #pragma unroll
    for (int p = 0; p < 4; ++p) {
        const int d = p * 32 + w * 4 + rg;
        const float4* wvr = (const float4*)(Wv + (size_t)(h * D_ + d) * E_);
        float pA = 0.f, pV = 0.f;
        #pragma unroll 4
        for (int i = 0; i < 16; ++i) {
            float4 wv4 = wvr[cl + i * 16];
            float4 pa = pooled4[cl + i * 16];
            float4 pb = pool24[cl + i * 16];
            pA += wv4.x * pa.x + wv4.y * pa.y + wv4.z * pa.z + wv4.w * pa.w;
            pV += wv4.x * pb.x + wv4.y * pb.y + wv4.z * pb.z + wv4.w * pb.w;
        }
        #pragma unroll
        for (int off = 8; off; off >>= 1) {
            pA += __shfl_xor(pA, off);
            pV += __shfl_xor(pV, off);
        }
        if (cl == 0) { attA_s[d] = pA; attV_s[d] = pV; }
    }
    __syncthreads();

    if (t < 128) {
        int ci = 0;
        #pragma unroll
        for (int i = 0; i < 8; ++i) ci += mask[b * N_ + t + i * 128];
        float cf = (float)ci;
        #pragma unroll
        for (int off = 32; off; off >>= 1) cf += __shfl_down(cf, off);
        if ((t & 63) == 0) red2[t >> 6] = cf;
        const float ss = ssumg[bh];
        att[t] = attA_s[t] + ss * bv[h * D_ + t];
    }
    __syncthreads();
    if (t == 0) cnt_s = red2[0] + red2[1];
    if (t < MID_) {
        float a = bb[t];
        #pragma unroll 4
        for (int d2 = 0; d2 < D_; ++d2) a += att[d2] * Wb[t * D_ + d2];
        hv[t] = fmaxf(a, 0.f);
    }
    __syncthreads();
    if (t < 128) {
        float z = bl2[t];
        #pragma unroll
        for (int m = 0; m < MID_; ++m) z += hv[m] * Wl2[t * MID_ + m];
        float alphac = 1.f / (1.f + expf(-z));
        const float bvd = bv[h * D_ + t];
        float v2a = attV_s[t] / cnt_s + bvd;
        out[(size_t)b * E_ + h * D_ + t] =
            value1[(size_t)b * E_ + h * D_ + t] * v2a * alphac;
    }
}

// ---------------------------------------------------------------------------
extern "C" void kernel_launch(void* const* d_in, const int* in_sizes, int n_in,
                              void* d_out, int out_size, void* d_ws, size_t ws_size,
                              hipStream_t stream)
{
    const float* query  = (const float*)d_in[0];
    const float* key    = (const float*)d_in[1];
    const int*   mask   = (const int*)d_in[2];
    const float* value1 = (const float*)d_in[3];
    const float* value2 = (const float*)d_in[4];
    const float* Wq  = (const float*)d_in[5];
    const float* bq  = (const float*)d_in[6];
    const float* Wk  = (const float*)d_in[7];
    const float* bk  = (const float*)d_in[8];
    const float* Wv  = (const float*)d_in[9];
    const float* bv  = (const float*)d_in[10];
    const float* Wb  = (const float*)d_in[11];
    const float* bb  = (const float*)d_in[12];
    // d_in[13] = Wl, d_in[14] = bl: eliminated (softmax of uniform = mask/cnt)
    const float* Wl2 = (const float*)d_in[15];
    const float* bl2 = (const float*)d_in[16];
    float* out = (float*)d_out;

    // workspace layout (bytes), ~35 MB
    char* ws = (char*)d_ws;
    const size_t SZ_PPP = (size_t)B_ * H_ * NT_ * E_ * 4;     // PPpart: 32 MB
    const size_t SZ_P2P = (size_t)8 * B_ * E_ * 4;            // P2p: 1 MB
    const size_t OFF_P2P = SZ_PPP;
    const size_t OFF_SS  = OFF_P2P + SZ_P2P;                  // ssum: 1 KB
    const size_t OFF_QB  = OFF_SS + 1024;                     // qb: 1 KB
    const size_t OFF_QS  = OFF_QB + 1024;                     // Qs: 128 KB
    const size_t OFF_QKB = OFF_QS + (size_t)B_ * E_ * 4;      // qkb: 512 KB
    float* PPpart = (float*)(ws);
    float* P2p    = (float*)(ws + OFF_P2P);
    float* ssum   = (float*)(ws + OFF_SS);
    float* qb     = (float*)(ws + OFF_QB);
    float* Qs     = (float*)(ws + OFF_QS);
    unsigned short* qkb = (unsigned short*)(ws + OFF_QKB);

    // zero atomic-accumulated regions: P2p + ssum + qb (contiguous)
    hipMemsetAsync(ws + OFF_P2P, 0, SZ_P2P + 2048, stream);

    hipLaunchKernelGGL(k_q, dim3(256 + NT_ * B_), dim3(256), 0, stream,
                       query, Wq, bq, bk, Qs, qb, value2, mask, P2p);
    hipLaunchKernelGGL(k_k, dim3(256), dim3(256), 0, stream,
                       Qs, Wk, qkb);
    hipLaunchKernelGGL(k_main, dim3(NT_, B_), dim3(256), 0, stream,
                       key, qkb, qb, PPpart, ssum);
    hipLaunchKernelGGL(k_tail, dim3(B_ * H_), dim3(512), 0, stream,
                       PPpart, P2p, ssum, mask, Wv, bv, Wb, bb, Wl2, bl2,
                       value1, out);
}